// Round 17
// baseline (77.272 us; speedup 1.0000x reference)
//
#include <hip/hip_runtime.h>
#include <math.h>

#define HIDDEN 1024
#define NL 9
#define LEAN_TAU 0.25f
#define LEAN_DELTA 0.35f
#define LCH 16
#define TFIX 512
#define TOKFIX 510  // T-2 compile-time: /TOKFIX lowers to magic-mul

typedef __attribute__((ext_vector_type(8))) short short8v;
typedef __attribute__((ext_vector_type(4))) float f32x4;
typedef __attribute__((ext_vector_type(4))) unsigned uint4v;
union frag_u { uint4v u; short8v s; };

// pack 2 fp32 -> 2 bf16 (truncation; validated end-to-end in R16, absmax 0)
__device__ __forceinline__ unsigned pk2(float a, float b) {
  return (__float_as_uint(b) & 0xffff0000u) | (__float_as_uint(a) >> 16);
}

// ---------------- Kernel 1: pipelined K-split MFMA logits -------------------
// R17 = R16 + (a) grid-stride 3 tiles/block (B-frags amortized), (b) T14
// async-STAGE: next tile's 16 row-loads issued into regs BEFORE current
// tile's MFMA, LDS-written after the post-MFMA barrier, (c) epilogue
// distributed: wave w handles C-row-quadrant j=w (4x parallel vs R16 wave0).
// 2 barriers/tile. VGPR ~145 (st 64 + bfrag 32), LDS 37.9KB.
__global__ __launch_bounds__(256) void mfma_k(
    const float* __restrict__ hs, const float* __restrict__ w,
    const float* __restrict__ bias, const int* __restrict__ amask,
    float* __restrict__ e, int B) {
  const int nTok = B * TOKFIX;
  const int nTile = nTok >> 4;  // exact: 32640 = 2040*16
  const int wave = threadIdx.x >> 6, lane = threadIdx.x & 63;
  const int g = lane >> 4, c = lane & 15;
  __shared__ unsigned short aw[4][16][264];  // per-wave bf16 A K-slice (+pad)
  __shared__ float4 cps[4][64];              // per-wave partial C

  // ---- B fragments once per block (R16-verified layout) ----
  frag_u bfrag[8];
  {
    const int brow = (c < NL) ? c : 0;
    const float* wp = w + (size_t)brow * HIDDEN + wave * 256 + g * 8;
#pragma unroll
    for (int s = 0; s < 8; ++s) {
      const float4 u0 = *reinterpret_cast<const float4*>(wp + s * 32);
      const float4 u1 = *reinterpret_cast<const float4*>(wp + s * 32 + 4);
      unsigned d0 = pk2(u0.x, u0.y), d1 = pk2(u0.z, u0.w);
      unsigned d2 = pk2(u1.x, u1.y), d3 = pk2(u1.z, u1.w);
      if (c >= NL) d0 = d1 = d2 = d3 = 0u;
      bfrag[s].u = uint4v{d0, d1, d2, d3};
    }
  }
  const float bc = (c < NL) ? bias[c] : 0.f;

  float4 st[16];  // staged next-tile rows (64 VGPR, in flight across compute)

#define LOADTILE(TT)                                                        \
  {                                                                         \
    int b_ = ((TT)*16) / TOKFIX, t_ = ((TT)*16) - b_ * TOKFIX;              \
    _Pragma("unroll") for (int j_ = 0; j_ < 16; ++j_) {                     \
      st[j_] = *reinterpret_cast<const float4*>(                            \
          hs + ((size_t)b_ * TFIX + t_ + 1) * HIDDEN + wave * 256 +         \
          lane * 4);                                                        \
      if (++t_ >= TOKFIX) { t_ = 0; ++b_; }                                 \
    }                                                                       \
  }
#define PACKWRITE()                                                         \
  {                                                                         \
    _Pragma("unroll") for (int j_ = 0; j_ < 16; ++j_) {                     \
      uint2 pk_;                                                            \
      pk_.x = pk2(st[j_].x, st[j_].y);                                      \
      pk_.y = pk2(st[j_].z, st[j_].w);                                      \
      *reinterpret_cast<uint2*>(&aw[wave][j_][lane * 4]) = pk_;             \
    }                                                                       \
  }

  int tile = blockIdx.x;
  if (tile >= nTile) return;
  LOADTILE(tile);
  PACKWRITE();
  __syncthreads();

  while (true) {
    const int tileN = tile + gridDim.x;
    const bool hasN = tileN < nTile;
    if (hasN) LOADTILE(tileN);  // issue early: in flight across MFMA+epilogue

    f32x4 acc = {0.f, 0.f, 0.f, 0.f};
#pragma unroll
    for (int s = 0; s < 8; ++s) {
      const short8v a =
          *reinterpret_cast<const short8v*>(&aw[wave][c][s * 32 + g * 8]);
      acc = __builtin_amdgcn_mfma_f32_16x16x32_bf16(a, bfrag[s].s, acc, 0, 0, 0);
    }
    cps[wave][lane] = *reinterpret_cast<float4*>(&acc);
    __syncthreads();

    // ---- distributed epilogue: this wave handles C rows g*4+wave ----
    {
      float v = bc;
#pragma unroll
      for (int k = 0; k < 4; ++k)
        v += reinterpret_cast<const float*>(&cps[k][lane])[wave];
      float m1 = (c < NL) ? v : -1e30f, m2 = -1e30f;
#pragma unroll
      for (int off = 1; off < 16; off <<= 1) {
        const float om1 = __shfl_xor(m1, off);
        const float om2 = __shfl_xor(m2, off);
        const float hi = fmaxf(m1, om1);
        const float lo = fminf(m1, om1);
        m2 = fmaxf(lo, fmaxf(m2, om2));
        m1 = hi;
      }
      const int tok = tile * 16 + g * 4 + wave;
      const int b = tok / TOKFIX, t = tok - b * TOKFIX;
      const bool unc = (m1 - m2 < LEAN_TAU) && (amask[b * TFIX + t + 1] != 0);
      const float vout = v + ((unc && c == 0) ? LEAN_DELTA : 0.f);
      if (c < NL && tok < nTok) e[(size_t)tok * NL + c] = vout;
    }
    if (hasN) PACKWRITE();  // vmcnt-wait here, after epilogue hid latency
    __syncthreads();
    if (!hasN) break;
    tile = tileN;
  }
#undef LOADTILE
#undef PACKWRITE
}

// ---------------- Kernel 2: per-chunk log-space matrix products -------------
__global__ __launch_bounds__(64) void chunk_k(
    const float* __restrict__ e, const int* __restrict__ labels,
    const float* __restrict__ trans, float* __restrict__ Pout,
    int B, int T, int C) {
  const int TOK = T - 2;
  __shared__ float e2[7][LCH][NL];
  __shared__ float tr2[NL * NL];
  __shared__ int msk[7][LCH];
  const int tid = threadIdx.x;
  const int nG = B * C;
  const int gbase = blockIdx.x * 7;

  for (int idx = tid; idx < NL * NL; idx += 64) tr2[idx] = trans[idx];
  for (int idx = tid; idx < 7 * LCH * NL; idx += 64) {
    const int sub = idx / (LCH * NL), rem = idx % (LCH * NL);
    const int step = rem / NL, j = rem % NL;
    const int g = gbase + sub;
    if (g < nG) {
      const int b = g / C, c = g % C;
      const int t = 1 + c * LCH + step;
      if (t < TOK) e2[sub][step][j] = e[((size_t)b * TOK + t) * NL + j];
    }
  }
  for (int idx = tid; idx < 7 * LCH; idx += 64) {
    const int sub = idx / LCH, step = idx % LCH;
    const int g = gbase + sub;
    if (g < nG) {
      const int b = g / C, c = g % C;
      const int t = 1 + c * LCH + step;
      msk[sub][step] = (t < TOK) ? (labels[(size_t)b * T + 1 + t] != -100) : 0;
    }
  }
  __syncthreads();

  const int sub = tid / NL, i = tid % NL;
  const int g = gbase + sub;
  const bool act = (sub < 7) && (g < nG);
  int len = 1;
  if (act) { const int c = g % C; len = min(LCH, TOK - (1 + c * LCH)); }

  float W[NL][NL];
#pragma unroll
  for (int k = 0; k < NL; ++k)
#pragma unroll
    for (int j = 0; j < NL; ++j) W[k][j] = __expf(tr2[k * NL + j]);

  float P[NL];
  {
    const int m0 = act ? msk[sub][0] : 0;
#pragma unroll
    for (int j = 0; j < NL; ++j)
      P[j] = m0 ? (tr2[i * NL + j] + e2[sub][0][j])
                : ((i == j) ? 0.f : -1e30f);
  }
  for (int step = 1; step < len; ++step) {
    const int mt = msk[sub][step];
    float mx = P[0];
#pragma unroll
    for (int k = 1; k < NL; ++k) mx = fmaxf(mx, P[k]);
    float E[NL];
#pragma unroll
    for (int k = 0; k < NL; ++k) E[k] = __expf(P[k] - mx);
    float Pn[NL];
#pragma unroll
    for (int j = 0; j < NL; ++j) {
      float s = 0.f;
#pragma unroll
      for (int k = 0; k < NL; ++k) s = fmaf(E[k], W[k][j], s);
      Pn[j] = mx + __logf(s) + e2[sub][step][j];
    }
#pragma unroll
    for (int j = 0; j < NL; ++j) P[j] = mt ? Pn[j] : P[j];
  }
  if (act) {
    float* dst = Pout + (size_t)g * 81 + i * NL;
#pragma unroll
    for (int j = 0; j < NL; ++j) dst[j] = P[j];
  }
}

// ---------------- Kernel 3: per-batch combine (num + den fold) --------------
__global__ __launch_bounds__(64) void combine_k(
    const float* __restrict__ e, const int* __restrict__ labels,
    const float* __restrict__ start_t, const float* __restrict__ end_t,
    const float* __restrict__ trans, const float* __restrict__ Pmat,
    float* __restrict__ llh, int B, int T, int C) {
  const int TOK = T - 2;
  const int b = blockIdx.x, lane = threadIdx.x;
  const float* eb = e + (size_t)b * TOK * NL;
  const int* lb = labels + (size_t)b * T + 1;

  const int g0r = lb[0];
  const int tg0 = (g0r == -100) ? 0 : g0r;
  float nsum = 0.f;
  int pack = -1;
  for (int t = 1 + lane; t < TOK; t += 64) {
    const int gr = lb[t], pr = lb[t - 1];
    if (gr != -100) {
      const int cur = gr;
      const int prev = (pr == -100) ? 0 : pr;
      nsum += trans[prev * NL + cur] + eb[t * NL + cur];
      pack = (t << 4) | cur;
    }
  }
#pragma unroll
  for (int off = 32; off; off >>= 1) {
    nsum += __shfl_xor(nsum, off);
    pack = max(pack, __shfl_xor(pack, off));
  }
  const int last = (pack < 0) ? tg0 : (pack & 15);
  const float num = start_t[tg0] + eb[tg0] + nsum + end_t[last];

  float alpha = (lane < NL) ? (start_t[lane] + eb[lane]) : -1e30f;
  for (int c = 0; c < C; ++c) {
    const float* Pc = Pmat + ((size_t)b * C + c) * 81;
    float col[NL];
#pragma unroll
    for (int i = 0; i < NL; ++i)
      col[i] = (lane < NL) ? Pc[i * NL + lane] : -1e30f;
    float s[NL];
    float mx = -1e30f;
#pragma unroll
    for (int i = 0; i < NL; ++i) {
      const float ai = __shfl(alpha, i);
      s[i] = ai + col[i];
      mx = fmaxf(mx, s[i]);
    }
    float sum = 0.f;
#pragma unroll
    for (int i = 0; i < NL; ++i) sum += __expf(s[i] - mx);
    const float nx = mx + __logf(sum);
    alpha = (lane < NL) ? nx : -1e30f;
  }
  const float v = (lane < NL) ? (alpha + end_t[lane]) : -1e30f;
  float mx = v;
#pragma unroll
  for (int off = 32; off; off >>= 1) mx = fmaxf(mx, __shfl_xor(mx, off));
  float sum = (lane < NL) ? __expf(v - mx) : 0.f;
#pragma unroll
  for (int off = 32; off; off >>= 1) sum += __shfl_xor(sum, off);
  const float den = mx + __logf(sum);
  if (lane == 0) llh[b] = num - den;
}

// ---------------- Kernel 4: -mean(llh) ----------------
__global__ __launch_bounds__(64) void reduce_k(const float* __restrict__ llh,
                                               float* __restrict__ out, int B) {
  float v = 0.f;
  for (int i = threadIdx.x; i < B; i += 64) v += llh[i];
#pragma unroll
  for (int off = 32; off; off >>= 1) v += __shfl_xor(v, off);
  if (threadIdx.x == 0) out[0] = -v / (float)B;
}

extern "C" void kernel_launch(void* const* d_in, const int* in_sizes, int n_in,
                              void* d_out, int out_size, void* d_ws,
                              size_t ws_size, hipStream_t stream) {
  const float* hs     = (const float*)d_in[0];
  const float* w      = (const float*)d_in[1];
  const float* bias   = (const float*)d_in[2];
  const float* st     = (const float*)d_in[3];
  const float* et     = (const float*)d_in[4];
  const float* tr     = (const float*)d_in[5];
  const int*   amask  = (const int*)d_in[6];
  const int*   labels = (const int*)d_in[7];

  const int T = 512;
  const int B = in_sizes[6] / T;
  const int TOK = T - 2;
  const int C = (TOK - 1 + LCH - 1) / LCH;

  float* e    = (float*)d_ws;                 // (B, TOK, 9)
  float* llh  = e + (size_t)B * TOK * NL;     // (B,)
  float* Pmat = llh + B;                      // (B*C, 81)

  const int nTok = B * TOK;
  const int nTile = (nTok + 15) / 16;         // 2040 for B=64
  int grid1 = 680;                            // 3 tiles/block (2040 = 680*3)
  if (grid1 > nTile) grid1 = nTile;
  mfma_k<<<grid1, 256, 0, stream>>>(hs, w, bias, amask, e, B);
  const int nG = B * C;
  chunk_k<<<(nG + 6) / 7, 64, 0, stream>>>(e, labels, tr, Pmat, B, T, C);
  combine_k<<<B, 64, 0, stream>>>(e, labels, st, et, tr, Pmat, llh, B, T, C);
  reduce_k<<<1, 64, 0, stream>>>(llh, (float*)d_out, B);
}